// Round 8
// baseline (38.585 us; speedup 1.0000x reference)
//
#include <hip/hip_runtime.h>
#include <math.h>

#define B_ 2
#define N_ 512
#define C_ 32
#define H_ 200
#define W_ 200
#define HW_ (H_*W_)
#define THRESH_ 0.05f
#define OUT_BEV (B_*C_*H_*W_)
#define NSEG 4                    // 4 waves/block, 128 gaussians each
#define TILES_PER_B 625           // 25x25 tiles of 8x8
#define LOG2E 1.4426950408889634f
#define LN2   0.6931471805599453f
#define REPS 4                    // DIAGNOSTIC: amplify kernel 4x to surface in rocprof top-5

typedef float v2f __attribute__((ext_vector_type(2)));

// Per-lane gaussian param compute + exact-ellipse-bbox tile-overlap test.
__device__ __forceinline__ bool pcompute(
    const float* __restrict__ m3, const float* __restrict__ cv,
    const float* __restrict__ opc, int i,
    float tu0, float tu1, float tv0, float tv1, float4& q0, float4& q1)
{
    float x  = m3[i*3 + 0];
    float y  = m3[i*3 + 1];
    float c0 = cv[i*6 + 0];
    float c1 = cv[i*6 + 1];
    float c3 = cv[i*6 + 3];
    float op = opc[i];
    float mu_u = 100.0f - 100.0f * y;
    float mu_v = 100.0f - 100.0f * x;
    float Cuu = 10000.0f * c3 + 0.3f;
    float Cvv = 10000.0f * c0 + 0.3f;
    float Cuv = 10000.0f * c1;
    float det = Cuu * Cvv - Cuv * Cuv;
    bool valid = det > 0.0f;
    float opac = (op > THRESH_) ? op : 0.0f;
    if (!valid) opac = 0.0f;
    float inv_det = valid ? (1.0f / det) : 0.0f;
    float a2 = -0.5f * LOG2E * (Cvv * inv_det);
    float b2 = -0.5f * LOG2E * (Cuu * inv_det);
    float c2 =  LOG2E * (Cuv * inv_det);
    float thr2 = 3.0e38f;
    bool ov = false;
    if (opac > 0.0f) {
        float r2 = log2f(255.0f * opac);          // > 0 since opac > 0.05
        thr2 = -r2;
        float rn = LN2 * r2;
        float du_max = sqrtf(fmaxf(2.0f * rn * Cuu, 0.0f)) + 1.0e-3f;
        float dv_max = sqrtf(fmaxf(2.0f * rn * Cvv, 0.0f)) + 1.0e-3f;
        ov = (mu_u - du_max <= tu1) & (mu_u + du_max >= tu0) &
             (mu_v - dv_max <= tv1) & (mu_v + dv_max >= tv0);
    }
    q0 = make_float4(mu_u, mu_v, a2, b2);
    q1 = make_float4(c2, opac, thr2, 0.0f);
    return ov;
}

// R6 structure exactly, body repeated REPS times (identical work+stores each
// rep; final rep leaves correct output). Blocks 0..1249: one 8x8 tile.
// Block 1250: count.
__global__ __launch_bounds__(256, 5) void render_kernel(
    const float* __restrict__ features,   // [B,N,C]
    const float* __restrict__ means3D,    // [B,N,3]
    const float* __restrict__ cov3D,      // [B,N,6]
    const float* __restrict__ opacities,  // [B,N,1]
    float* __restrict__ out)              // [B,C,H,W] + 1 scalar
{
    __shared__ float s_T[NSEG][64];            // 1 KB
    __shared__ float s_W[NSEG * 64];           // 1 KB
    __shared__ float4 u_mem[NSEG * 128 * 2];   // 16 KB union: hit params | s_acc
    float4* s_hit = u_mem;
    float (*s_acc)[16][64] = (float (*)[16][64])u_mem;   // [NSEG][16][64]

    int blk = blockIdx.x;
    int tid = threadIdx.x;

    if (blk == B_ * TILES_PER_B) {             // ---- count-only block ----
        for (int rep = 0; rep < REPS; ++rep) {
            int cnt = ((opacities[tid]       > THRESH_) ? 1 : 0)
                    + ((opacities[tid + 256] > THRESH_) ? 1 : 0)
                    + ((opacities[tid + 512] > THRESH_) ? 1 : 0)
                    + ((opacities[tid + 768] > THRESH_) ? 1 : 0);
            for (int off = 32; off > 0; off >>= 1) cnt += __shfl_down(cnt, off);
            int* s_red = (int*)s_W;
            if ((tid & 63) == 0) s_red[tid >> 6] = cnt;
            __syncthreads();
            if (tid == 0)
                out[OUT_BEV] = (float)(s_red[0] + s_red[1] + s_red[2] + s_red[3]) * 0.5f;
            __syncthreads();
        }
        return;
    }

    int b  = blk / TILES_PER_B;
    int t  = blk - b * TILES_PER_B;
    int tu = t / 25;
    int tv = t - tu * 25;
    int wave = __builtin_amdgcn_readfirstlane(tid >> 6);   // uniform
    int lane = tid & 63;

    float tu0 = (float)(tu * 8), tu1 = tu0 + 7.0f;
    float tv0 = (float)(tv * 8), tv1 = tv0 + 7.0f;

    for (int rep = 0; rep < REPS; ++rep) {
        // ---- per-lane params for the wave's two 64-gaussian halves ----
        float4 qA0, qA1, qB0, qB1;
        int i0 = b * N_ + wave * 128 + lane;
        bool ovA = pcompute(means3D, cov3D, opacities, i0,      tu0, tu1, tv0, tv1, qA0, qA1);
        bool ovB = pcompute(means3D, cov3D, opacities, i0 + 64, tu0, tu1, tv0, tv1, qB0, qB1);
        unsigned long long m0 = __ballot(ovA);
        unsigned long long m1 = __ballot(ovB);

        // ---- order-preserving compaction of hit params into LDS slots ----
        int sbase = wave * 256;                // float4 units (128 slots * 2)
        {
            int posA = __builtin_amdgcn_mbcnt_hi((unsigned)(m0 >> 32),
                       __builtin_amdgcn_mbcnt_lo((unsigned)m0, 0));
            if (ovA) { int s = sbase + 2 * posA; s_hit[s] = qA0; s_hit[s + 1] = qA1; }
            int cA = __popcll(m0);
            int posB = __builtin_amdgcn_mbcnt_hi((unsigned)(m1 >> 32),
                       __builtin_amdgcn_mbcnt_lo((unsigned)m1, 0));
            if (ovB) { int s = sbase + 2 * (cA + posB); s_hit[s] = qB0; s_hit[s + 1] = qB1; }
        }

        int uu = tu * 8 + (lane >> 3);
        int vv = tv * 8 + (lane & 7);
        float u = (float)uu, v = (float)vv;

        float T = 1.0f;
        v2f acc2[16];
#pragma unroll
        for (int i = 0; i < 16; ++i) acc2[i] = (v2f){0.0f, 0.0f};

        const float* featB = features + (size_t)b * (N_ * C_);
        int nh = __builtin_amdgcn_readfirstlane(__popcll(m0) + __popcll(m1));
        unsigned long long w0 = m0, w1 = m1;
        int nbase = wave * 128;

        // ---- counted, branchless, unrolled hit loop ----
#pragma unroll 2
        for (int k = 0; k < nh; ++k) {
            float4 q0 = s_hit[sbase + 2 * k];  // broadcast ds_read
            float4 q1 = s_hit[sbase + 2 * k + 1];
            bool useA = (w0 != 0ull);
            unsigned long long m = useA ? w0 : w1;
            int j = __builtin_ctzll(m);
            int n = nbase + (useA ? j : 64 + j);
            if (useA) w0 &= w0 - 1; else w1 &= w1 - 1;
            n = __builtin_amdgcn_readfirstlane(n);
            const v2f* f2 = (const v2f*)(featB + (size_t)n * C_);   // s_load
            float du = u - q0.x;
            float dv = v - q0.y;
            float pw = fmaf(q0.z * du, du, fmaf(q0.w * dv, dv, q1.x * (du * dv)));
            bool hit = (pw <= 0.0f) && (pw >= q1.z);
            float al = hit ? fminf(0.99f, q1.y * exp2f(pw)) : 0.0f;
            float wgt = T * al;
            v2f w2 = {wgt, wgt};
#pragma unroll
            for (int i = 0; i < 16; ++i)
                acc2[i] = __builtin_elementwise_fma(w2, f2[i], acc2[i]);
            T *= (1.0f - al);
        }

        // ---- combine: prefix transmittance + 2 channel-rounds through LDS --
        s_T[wave][lane] = T;
        __syncthreads();                        // hit loops done; u_mem reusable

        {
            float Wg = 1.0f;
            for (int g = 0; g < wave; ++g) Wg *= s_T[g][lane];
            s_W[wave * 64 + lane] = Wg;
        }

        size_t obase = (size_t)b * C_ * HW_ + (size_t)(tu * 8) * W_ + (size_t)(tv * 8);
        size_t opix  = (size_t)(lane >> 3) * W_ + (lane & 7);
#pragma unroll
        for (int k = 0; k < 2; ++k) {
#pragma unroll
            for (int cc = 0; cc < 8; ++cc) {
                v2f a = acc2[k * 8 + cc];
                s_acc[wave][cc * 2][lane]     = a.x;
                s_acc[wave][cc * 2 + 1][lane] = a.y;
            }
            __syncthreads();                    // s_acc (and s_W on k==0) visible
            float vq[4];
#pragma unroll
            for (int q = 0; q < 4; ++q) {
                float s = 0.0f;
#pragma unroll
                for (int g = 0; g < NSEG; ++g)
                    s = fmaf(s_W[g * 64 + lane], s_acc[g][wave * 4 + q][lane], s);
                vq[q] = s;
            }
#pragma unroll
            for (int q = 0; q < 4; ++q)
                out[obase + (size_t)(k * 16 + wave * 4 + q) * HW_ + opix] = vq[q];
            __syncthreads();                    // reads done before reuse (next round/rep)
        }
    }
}

extern "C" void kernel_launch(void* const* d_in, const int* in_sizes, int n_in,
                              void* d_out, int out_size, void* d_ws, size_t ws_size,
                              hipStream_t stream) {
    const float* features  = (const float*)d_in[0];
    const float* means3D   = (const float*)d_in[1];
    const float* cov3D     = (const float*)d_in[2];
    const float* opacities = (const float*)d_in[3];
    float* out = (float*)d_out;
    render_kernel<<<B_ * TILES_PER_B + 1, 256, 0, stream>>>(
        features, means3D, cov3D, opacities, out);
}

// Round 9
// 16.841 us; speedup vs baseline: 2.2911x; 2.2911x over previous
//
#include <hip/hip_runtime.h>
#include <math.h>

#define B_ 2
#define N_ 512
#define C_ 32
#define H_ 200
#define W_ 200
#define HW_ (H_*W_)
#define THRESH_ 0.05f
#define OUT_BEV (B_*C_*H_*W_)
#define NSEG 4                    // 4 waves/block, 128 gaussians each
#define TILES_PER_B 625           // 25x25 tiles of 8x8
#define LOG2E 1.4426950408889634f
#define LN2   0.6931471805599453f

typedef float v2f __attribute__((ext_vector_type(2)));

__device__ __forceinline__ float rlane(float x, int l) {
    return __int_as_float(__builtin_amdgcn_readlane(__float_as_int(x), l));
}

// Per-lane gaussian param compute + exact-ellipse-bbox tile-overlap test.
__device__ __forceinline__ bool pcompute(
    const float* __restrict__ m3, const float* __restrict__ cv,
    const float* __restrict__ opc, int i,
    float tu0, float tu1, float tv0, float tv1,
    float& mu_u, float& mu_v, float& a2, float& b2, float& c2,
    float& opo, float& thr2)
{
    float x  = m3[i*3 + 0];
    float y  = m3[i*3 + 1];
    float c0 = cv[i*6 + 0];
    float c1 = cv[i*6 + 1];
    float c3 = cv[i*6 + 3];
    float op = opc[i];
    mu_u = 100.0f - 100.0f * y;
    mu_v = 100.0f - 100.0f * x;
    float Cuu = 10000.0f * c3 + 0.3f;
    float Cvv = 10000.0f * c0 + 0.3f;
    float Cuv = 10000.0f * c1;
    float det = Cuu * Cvv - Cuv * Cuv;
    bool valid = det > 0.0f;
    float opac = (op > THRESH_) ? op : 0.0f;
    if (!valid) opac = 0.0f;
    float inv_det = valid ? (1.0f / det) : 0.0f;
    a2 = -0.5f * LOG2E * (Cvv * inv_det);
    b2 = -0.5f * LOG2E * (Cuu * inv_det);
    c2 =  LOG2E * (Cuv * inv_det);
    opo = opac;
    if (opac > 0.0f) {
        float r2 = log2f(255.0f * opac);          // > 0 since opac > 0.05
        thr2 = -r2;
        float rn = LN2 * r2;
        float du_max = sqrtf(fmaxf(2.0f * rn * Cuu, 0.0f)) + 1.0e-3f;
        float dv_max = sqrtf(fmaxf(2.0f * rn * Cvv, 0.0f)) + 1.0e-3f;
        return (mu_u - du_max <= tu1) & (mu_u + du_max >= tu0) &
               (mu_v - dv_max <= tv1) & (mu_v + dv_max >= tv0);
    }
    thr2 = 3.0e38f;
    return false;
}

// Walk a 64-bit hit mask two gaussians at a time (ctz ascending = order
// preserved). Params broadcast via readlane; feature rows wave-uniform ->
// s_load; both rows issued before the FMA block. pk-FMA accumulation.
#define WALK(mask, P, base_n)                                                \
    while (mask) {                                                           \
        int j0 = __builtin_ctzll(mask); mask &= mask - 1;                    \
        bool two = (mask != 0ull);                                           \
        int j1 = two ? __builtin_ctzll(mask) : j0;                           \
        if (two) mask &= mask - 1;                                           \
        float mu_u0 = rlane(P##_mu_u, j0), mu_v0 = rlane(P##_mu_v, j0);      \
        float a0 = rlane(P##_a, j0), b0 = rlane(P##_b, j0);                  \
        float c0 = rlane(P##_c, j0), op0 = rlane(P##_op, j0);                \
        float th0 = rlane(P##_th, j0);                                       \
        float mu_u1 = rlane(P##_mu_u, j1), mu_v1 = rlane(P##_mu_v, j1);      \
        float a1 = rlane(P##_a, j1), b1 = rlane(P##_b, j1);                  \
        float c1 = rlane(P##_c, j1), op1 = rlane(P##_op, j1);                \
        float th1 = rlane(P##_th, j1);                                       \
        const v2f* f0 = (const v2f*)(featB + (size_t)((base_n) + j0) * C_);  \
        const v2f* f1 = (const v2f*)(featB + (size_t)((base_n) + j1) * C_);  \
        float du0 = u - mu_u0, dv0 = v - mu_v0;                              \
        float pw0 = fmaf(a0 * du0, du0, fmaf(b0 * dv0, dv0, c0 * (du0 * dv0))); \
        bool hit0 = (pw0 <= 0.0f) && (pw0 >= th0);                           \
        float al0 = hit0 ? fminf(0.99f, op0 * exp2f(pw0)) : 0.0f;            \
        float du1 = u - mu_u1, dv1 = v - mu_v1;                              \
        float pw1 = fmaf(a1 * du1, du1, fmaf(b1 * dv1, dv1, c1 * (du1 * dv1))); \
        bool hit1 = two && (pw1 <= 0.0f) && (pw1 >= th1);                    \
        float al1 = hit1 ? fminf(0.99f, op1 * exp2f(pw1)) : 0.0f;            \
        if (__any(hit0 | hit1)) {                                            \
            float w0 = T * al0;                                              \
            float Tm = T * (1.0f - al0);                                     \
            float w1 = Tm * al1;                                             \
            T = Tm * (1.0f - al1);                                           \
            v2f w0v = {w0, w0}, w1v = {w1, w1};                              \
            _Pragma("unroll")                                                \
            for (int i = 0; i < 16; ++i)                                     \
                acc2[i] = __builtin_elementwise_fma(w1v, f1[i],              \
                          __builtin_elementwise_fma(w0v, f0[i], acc2[i]));   \
        }                                                                    \
    }

// Blocks 0..1249: one 8x8 tile (4 waves x 128-gaussian ordered segments;
// readlane param broadcast; single-barrier bf16-staged combine).
// Block 1250: num_gaussians scalar.
__global__ __launch_bounds__(256, 5) void render_kernel(
    const float* __restrict__ features,   // [B,N,C]
    const float* __restrict__ means3D,    // [B,N,3]
    const float* __restrict__ cov3D,      // [B,N,6]
    const float* __restrict__ opacities,  // [B,N,1]
    float* __restrict__ out)              // [B,C,H,W] + 1 scalar
{
    __shared__ float s_T[NSEG][64];                 // 1 KB
    __shared__ unsigned int s_pk[NSEG * 16 * 64];   // 16 KB: bf16x2 partials

    int blk = blockIdx.x;
    int tid = threadIdx.x;

    if (blk == B_ * TILES_PER_B) {           // ---- count-only block ----
        int cnt = ((opacities[tid]       > THRESH_) ? 1 : 0)
                + ((opacities[tid + 256] > THRESH_) ? 1 : 0)
                + ((opacities[tid + 512] > THRESH_) ? 1 : 0)
                + ((opacities[tid + 768] > THRESH_) ? 1 : 0);
        for (int off = 32; off > 0; off >>= 1) cnt += __shfl_down(cnt, off);
        int* s_red = (int*)s_T;
        if ((tid & 63) == 0) s_red[tid >> 6] = cnt;
        __syncthreads();
        if (tid == 0)
            out[OUT_BEV] = (float)(s_red[0] + s_red[1] + s_red[2] + s_red[3]) * 0.5f;
        return;
    }

    int b  = blk / TILES_PER_B;
    int t  = blk - b * TILES_PER_B;
    int tu = t / 25;
    int tv = t - tu * 25;
    int wave = __builtin_amdgcn_readfirstlane(tid >> 6);   // uniform
    int lane = tid & 63;

    float tu0 = (float)(tu * 8), tu1 = tu0 + 7.0f;
    float tv0 = (float)(tv * 8), tv1 = tv0 + 7.0f;

    // ---- per-lane params for the wave's two 64-gaussian halves ----
    float A_mu_u, A_mu_v, A_a, A_b, A_c, A_op, A_th;
    float B_mu_u, B_mu_v, B_a, B_b, B_c, B_op, B_th;
    int i0 = b * N_ + wave * 128 + lane;
    bool ovA = pcompute(means3D, cov3D, opacities, i0,      tu0, tu1, tv0, tv1,
                        A_mu_u, A_mu_v, A_a, A_b, A_c, A_op, A_th);
    bool ovB = pcompute(means3D, cov3D, opacities, i0 + 64, tu0, tu1, tv0, tv1,
                        B_mu_u, B_mu_v, B_a, B_b, B_c, B_op, B_th);
    unsigned long long m0 = __ballot(ovA);
    unsigned long long m1 = __ballot(ovB);

    int uu = tu * 8 + (lane >> 3);
    int vv = tv * 8 + (lane & 7);
    float u = (float)uu, v = (float)vv;

    float T = 1.0f;
    v2f acc2[16];
#pragma unroll
    for (int i = 0; i < 16; ++i) acc2[i] = (v2f){0.0f, 0.0f};
    const float* featB = features + (size_t)b * (N_ * C_);

    // ---- ordered hit loops: two 64-gaussian halves of this segment ----
    WALK(m0, A, wave * 128)
    WALK(m1, B, wave * 128 + 64)

    // ---- single-barrier combine: bf16-pack partials, stage, sync, reduce --
    s_T[wave][lane] = T;
#pragma unroll
    for (int i = 0; i < 16; ++i) {
        unsigned int r;
        asm("v_cvt_pk_bf16_f32 %0, %1, %2"
            : "=v"(r) : "v"(acc2[i].x), "v"(acc2[i].y));
        s_pk[(wave * 16 + i) * 64 + lane] = r;
    }
    __syncthreads();                       // the ONLY barrier

    // prefix transmittance weights for pixel = lane
    float t0g = s_T[0][lane], t1g = s_T[1][lane], t2g = s_T[2][lane];
    float Wg[NSEG];
    Wg[0] = 1.0f;
    Wg[1] = t0g;
    Wg[2] = t0g * t1g;
    Wg[3] = Wg[2] * t2g;

    // thread (wave,lane) combines channel-pairs wave*4..wave*4+3 at pixel lane
    size_t obase = (size_t)b * C_ * HW_ + (size_t)(tu * 8) * W_ + (size_t)(tv * 8);
    size_t opix  = (size_t)(lane >> 3) * W_ + (lane & 7);
#pragma unroll
    for (int q = 0; q < 4; ++q) {
        int pr = wave * 4 + q;             // packed pair -> channels 2pr, 2pr+1
        float vlo = 0.0f, vhi = 0.0f;
#pragma unroll
        for (int g = 0; g < NSEG; ++g) {
            unsigned int r = s_pk[(g * 16 + pr) * 64 + lane];
            float flo = __uint_as_float(r << 16);          // bf16(acc.x)
            float fhi = __uint_as_float(r & 0xffff0000u);  // bf16(acc.y)
            vlo = fmaf(Wg[g], flo, vlo);
            vhi = fmaf(Wg[g], fhi, vhi);
        }
        out[obase + (size_t)(2 * pr)     * HW_ + opix] = vlo;
        out[obase + (size_t)(2 * pr + 1) * HW_ + opix] = vhi;
    }
}

extern "C" void kernel_launch(void* const* d_in, const int* in_sizes, int n_in,
                              void* d_out, int out_size, void* d_ws, size_t ws_size,
                              hipStream_t stream) {
    const float* features  = (const float*)d_in[0];
    const float* means3D   = (const float*)d_in[1];
    const float* cov3D     = (const float*)d_in[2];
    const float* opacities = (const float*)d_in[3];
    float* out = (float*)d_out;
    render_kernel<<<B_ * TILES_PER_B + 1, 256, 0, stream>>>(
        features, means3D, cov3D, opacities, out);
}